// Round 1
// baseline (177.033 us; speedup 1.0000x reference)
//
#include <hip/hip_runtime.h>
#include <stdint.h>

#define HBINS 8192
#define HSHIFT 19
#define CAND 2048
#define NSLICES 16
#define HTHREADS 256
#define CTHREADS 256
#define STHREADS 1024

typedef unsigned int u32;
typedef unsigned long long u64;

// order-preserving float->uint map (ascending uint == ascending float)
__device__ __forceinline__ u32 f2s(float f) {
  u32 b = __float_as_uint(f);
  return b ^ ((b & 0x80000000u) ? 0xFFFFFFFFu : 0x80000000u);
}
__device__ __forceinline__ float s2f(u32 s) {
  u32 b = (s & 0x80000000u) ? (s ^ 0x80000000u) : ~s;
  return __uint_as_float(b);
}
__device__ __forceinline__ u32 rotl32(u32 x, int r) { return (x << r) | (x >> (32 - r)); }

__device__ __forceinline__ u64 shfl_xor_u64(u64 v, int mask) {
  int lo = __shfl_xor((int)(u32)v, mask, 64);
  int hi = __shfl_xor((int)(u32)(v >> 32), mask, 64);
  return ((u64)(u32)hi << 32) | (u32)lo;
}

// JAX threefry2x32, partitionable counter mode, key = jax.random.key(42) -> (0,42).
__device__ __forceinline__ u32 threefry_bits(u32 ctr) {
  const u32 ks0 = 0u, ks1 = 42u, ks2 = 0x1BD11BDAu ^ 0u ^ 42u;
  u32 x0 = ks0;
  u32 x1 = ctr + ks1;
#define TFR(r) { x0 += x1; x1 = rotl32(x1, (r)); x1 ^= x0; }
  TFR(13) TFR(15) TFR(26) TFR(6)   x0 += ks1; x1 += ks2 + 1u;
  TFR(17) TFR(29) TFR(16) TFR(24)  x0 += ks2; x1 += ks0 + 2u;
  TFR(13) TFR(15) TFR(26) TFR(6)   x0 += ks0; x1 += ks1 + 3u;
  TFR(17) TFR(29) TFR(16) TFR(24)  x0 += ks1; x1 += ks2 + 4u;
  TFR(13) TFR(15) TFR(26) TFR(6)   x0 += ks2; x1 += ks0 + 5u;
#undef TFR
  return x0 ^ x1;
}

// ---------------- zero hist scratch -------------------------------------------
__global__ __launch_bounds__(1024)
void zero_kernel(u32* __restrict__ p, int n) {
  int i = blockIdx.x * 1024 + threadIdx.x;
  if (i < n) p[i] = 0u;
}

// ---------------- per-slice raw-logit histogram (full machine) ----------------
// 8192 bins, packed u16 counts (per-slice count <= slice_len=8000 < 2^16, so no
// cross-field carry), 2 interleaved copies selected by tid&1 to split hot-bin
// same-address atomic streams across lane-parity halves of each wave.
// LDS layout: pair p (bins 2p,2p+1), copy c at hp[2p+c] -> adjacent banks.
__global__ __launch_bounds__(HTHREADS)
void hist_kernel(const float* __restrict__ logits, u32* __restrict__ ghist,
                 int V, int slice_len) {
  const int row = blockIdx.x / NSLICES;
  const int sl  = blockIdx.x % NSLICES;
  const int tid = threadIdx.x;
  __shared__ u32 hp[HBINS];   // HBINS/2 pairs * 2 copies = HBINS u32 = 32 KB
  for (int i = tid; i < HBINS; i += HTHREADS) hp[i] = 0u;
  __syncthreads();
  int rem = V - sl * slice_len;
  if (rem > slice_len) rem = slice_len;
  if (rem < 0) rem = 0;
  const float* src = logits + (size_t)row * (size_t)V + (size_t)sl * slice_len;
  const u32 c = (u32)(tid & 1);
  const int n4 = rem >> 2;
  const float4* p4 = (const float4*)src;
  for (int i = tid; i < n4; i += HTHREADS) {
    float4 w = p4[i];
    u32 b0 = f2s(w.x) >> HSHIFT;
    u32 b1 = f2s(w.y) >> HSHIFT;
    u32 b2 = f2s(w.z) >> HSHIFT;
    u32 b3 = f2s(w.w) >> HSHIFT;
    atomicAdd(&hp[(b0 & ~1u) | c], 1u << ((b0 & 1u) << 4));
    atomicAdd(&hp[(b1 & ~1u) | c], 1u << ((b1 & 1u) << 4));
    atomicAdd(&hp[(b2 & ~1u) | c], 1u << ((b2 & 1u) << 4));
    atomicAdd(&hp[(b3 & ~1u) | c], 1u << ((b3 & 1u) << 4));
  }
  for (int i = (n4 << 2) + tid; i < rem; i += HTHREADS) {
    u32 b = f2s(src[i]) >> HSHIFT;
    atomicAdd(&hp[(b & ~1u) | c], 1u << ((b & 1u) << 4));
  }
  __syncthreads();
  u32* gh = ghist + (size_t)row * HBINS;
  for (int p = tid; p < HBINS / 2; p += HTHREADS) {
    u32 s = hp[2 * p] + hp[2 * p + 1];   // fieldwise sum: each field < 2^16
    if (s) {
      u32 lo = s & 0xFFFFu;
      u32 hi = s >> 16;
      if (lo) atomicAdd(&gh[2 * p], lo);       // sparse merge
      if (hi) atomicAdd(&gh[2 * p + 1], hi);
    }
  }
}

// ---------------- per-row threshold select (tiny) -----------------------------
__global__ __launch_bounds__(256)
void select_kernel(const u32* __restrict__ ghist, const int* __restrict__ topks,
                   u32* __restrict__ gthr, u32* __restrict__ gcs,
                   u32* __restrict__ gcount, int V) {
  const int row = blockIdx.x;
  const int tid = threadIdx.x;
  __shared__ u32 hist[HBINS];   // 32 KB
  __shared__ u32 part[256];     // 32 bins each
  __shared__ u32 chunk[64];     // 128 bins each
  const u32* gh = ghist + (size_t)row * HBINS;
  for (int i = tid; i < HBINS; i += 256) hist[i] = gh[i];
  __syncthreads();
  {
    u32 s = 0;
    for (int j = 0; j < 32; ++j) s += hist[tid * 32 + j];
    part[tid] = s;
  }
  __syncthreads();
  if (tid < 64) {
    chunk[tid] = part[tid * 4] + part[tid * 4 + 1] + part[tid * 4 + 2] + part[tid * 4 + 3];
  }
  __syncthreads();
  if (tid == 0) {
    int k = topks[row];
    if (k < 1) k = 1;
    if (k > V) k = V;
    const u32 ku = (u32)k;
    u32 acc = 0;
    int cstar = 0;
    for (int c = 63; c >= 0; --c) {
      if (acc + chunk[c] >= ku) { cstar = c; break; }
      acc += chunk[c];
    }
    int pstar = cstar * 4;
    for (int p = cstar * 4 + 3; p >= cstar * 4; --p) {
      if (acc + part[p] >= ku) { pstar = p; break; }
      acc += part[p];
    }
    int bstar = pstar * 32;
    for (int bq = pstar * 32 + 31; bq >= pstar * 32; --bq) {
      acc += hist[bq];
      if (acc >= ku) { bstar = bq; break; }
    }
    gthr[row] = (u32)bstar << HSHIFT;
    gcs[row] = (acc < (u32)CAND ? acc : (u32)CAND);
    gcount[row] = 0u;
  }
}

// ---------------- per-slice collect (full machine, no hist traffic) -----------
__global__ __launch_bounds__(CTHREADS)
void collect_kernel(const float* __restrict__ logits,
                    const float* __restrict__ temps,
                    const u32* __restrict__ gthr,
                    u32* __restrict__ gcount,
                    u64* __restrict__ gcand, int V, int slice_len) {
  const int row = blockIdx.x / NSLICES;
  const int sl  = blockIdx.x % NSLICES;
  const int tid = threadIdx.x;

  __shared__ u64 stage[CAND];
  __shared__ int sh_cnt, sh_base;
  if (tid == 0) sh_cnt = 0;
  __syncthreads();

  const u32 thr = gthr[row];
  const float t = temps[row];
  int rem = V - sl * slice_len;
  if (rem > slice_len) rem = slice_len;
  if (rem < 0) rem = 0;
  const float* src = logits + (size_t)row * (size_t)V + (size_t)sl * slice_len;
  const u32 ibase = (u32)(sl * slice_len);
  const int n4 = rem >> 2;
  const float4* p4 = (const float4*)src;
  for (int i = tid; i < n4; i += CTHREADS) {
    float4 w = p4[i];
    if (f2s(w.x) >= thr) { int pos = atomicAdd(&sh_cnt, 1); if (pos < CAND) stage[pos] = ((u64)f2s(w.x / t) << 32) | (ibase + 4u * i + 0u); }
    if (f2s(w.y) >= thr) { int pos = atomicAdd(&sh_cnt, 1); if (pos < CAND) stage[pos] = ((u64)f2s(w.y / t) << 32) | (ibase + 4u * i + 1u); }
    if (f2s(w.z) >= thr) { int pos = atomicAdd(&sh_cnt, 1); if (pos < CAND) stage[pos] = ((u64)f2s(w.z / t) << 32) | (ibase + 4u * i + 2u); }
    if (f2s(w.w) >= thr) { int pos = atomicAdd(&sh_cnt, 1); if (pos < CAND) stage[pos] = ((u64)f2s(w.w / t) << 32) | (ibase + 4u * i + 3u); }
  }
  for (int i = (n4 << 2) + tid; i < rem; i += CTHREADS) {
    float l = src[i];
    if (f2s(l) >= thr) { int pos = atomicAdd(&sh_cnt, 1); if (pos < CAND) stage[pos] = ((u64)f2s(l / t) << 32) | (ibase + (u32)i); }
  }
  __syncthreads();
  int n = sh_cnt;
  if (n > CAND) n = CAND;
  if (tid == 0) sh_base = (int)atomicAdd(&gcount[row], (u32)n);
  __syncthreads();
  const int base = sh_base;
  u64* gc = gcand + (size_t)row * CAND;
  for (int i = tid; i < n; i += CTHREADS) {
    int dst = base + i;
    if (dst < CAND) gc[dst] = stage[i];
  }
}

// ---------------- per-row: hybrid reg/LDS sort + softmax chain + gumbel -------
__global__ __launch_bounds__(STHREADS)
void Sampler_73529840107542_kernel(const float* __restrict__ minps,
                                   const float* __restrict__ topps,
                                   const int* __restrict__ topks,
                                   const u32* __restrict__ gcs,
                                   const u64* __restrict__ gcand,
                                   int* __restrict__ out, int V) {
  const int b = blockIdx.x;
  const int tid = threadIdx.x;
  const int w = tid >> 6;
  const int l = tid & 63;
  const float one_minus_p = 1.0f - topps[b];
  const float minp = minps[b];
  int k = topks[b];
  if (k < 1) k = 1;
  if (k > V) k = V;

  __shared__ __align__(16) unsigned char arena[34816];
  u64* cand   = (u64*)(arena);              // [0,16384)
  float* bufA = (float*)(arena + 16384);    // [16384,24576) e / p
  float* bufB = (float*)(arena + 24576);    // [24576,32768) cumsum
  unsigned char* keepf = arena + 32768;     // [32768,34816)
  u64* red64  = (u64*)(arena + 16384);      // aliases bufA (argmax stage)
  float* redA = (float*)(arena + 16384);    // aliases bufA (Z2 stage)
  float* redB = (float*)(arena + 24576);    // aliases bufB (Z1 stage)

  __shared__ int sh_lb;
  __shared__ u32 sh_Ts;
  __shared__ float sh_m, sh_Z1, sh_Z2;

  const int cs = (int)gcs[b];
  const u64* gc = gcand + (size_t)b * CAND;
  const int e_lo = (w << 7) + l;      // wave w owns elements [w*128, w*128+128)
  const int e_hi = e_lo + 64;
  const u64 SENT = 0xFFFFFFFFFFFFFFFFull;
  u64 k0 = (e_lo < cs) ? gc[e_lo] : SENT;
  u64 k1 = (e_hi < cs) ? gc[e_hi] : SENT;

  // bitonic sort over the smallest power-of-2 span P >= cs (uniform per block;
  // slots [cs,P) hold SENT so [0,cs) ends up ascending == JAX stable argsort).
  // strides <=32: shfl_xor; stride 64: register swap; strides >=128: LDS.
  int P = 64;
  while (P < cs) P <<= 1;
  for (int size = 2; size <= P; size <<= 1) {
    for (int s = size >> 1; s > 0; s >>= 1) {
      if (s >= 128) {
        cand[e_lo] = k0; cand[e_hi] = k1;
        __syncthreads();
        u64 p0 = cand[e_lo ^ s], p1 = cand[e_hi ^ s];
        {
          bool keepmin = (((e_lo & s) == 0) == ((e_lo & size) == 0));
          if (keepmin ? (p0 < k0) : (p0 > k0)) k0 = p0;
        }
        {
          bool keepmin = (((e_hi & s) == 0) == ((e_hi & size) == 0));
          if (keepmin ? (p1 < k1) : (p1 > k1)) k1 = p1;
        }
        __syncthreads();
      } else if (s == 64) {
        bool asc = ((e_lo & size) == 0);   // e_hi has same direction (size>=128)
        if ((k0 > k1) == asc) { u64 t = k0; k0 = k1; k1 = t; }
      } else {
        u64 p0 = shfl_xor_u64(k0, s);
        u64 p1 = shfl_xor_u64(k1, s);
        {
          bool keepmin = (((l & s) == 0) == ((e_lo & size) == 0));
          if (keepmin ? (p0 < k0) : (p0 > k0)) k0 = p0;
        }
        {
          bool keepmin = (((l & s) == 0) == ((e_hi & size) == 0));
          if (keepmin ? (p1 < k1) : (p1 > k1)) k1 = p1;
        }
      }
    }
  }
  cand[e_lo] = k0; cand[e_hi] = k1;
  __syncthreads();

  if (tid == 0) {
    int ti = cs - k; if (ti < 0) ti = 0;
    sh_Ts = (u32)(cand[ti] >> 32);             // k-th largest x (exact)
    sh_m  = s2f((u32)(cand[cs - 1] >> 32));    // row max
  }
  __syncthreads();
  const u32 Ts = sh_Ts;
  const float m = sh_m;

  // first survivor slot (values >= Ts form a contiguous suffix of [0,cs))
  for (int c = tid; c < cs; c += STHREADS) {
    u32 s = (u32)(cand[c] >> 32);
    if (s >= Ts && (c == 0 || (u32)(cand[c - 1] >> 32) < Ts)) sh_lb = c;
  }
  __syncthreads();
  const int lb = sh_lb;

  // e = exp(x - m); exact 0 for masked / pad
  for (int c = tid; c < CAND; c += STHREADS) {
    float e = 0.0f;
    if (c < cs) {
      u32 s = (u32)(cand[c] >> 32);
      if (s >= Ts) e = expf(s2f(s) - m);
    }
    bufA[c] = e;
  }
  __syncthreads();

  // Z1 tree reduce (association identical to round 3)
  {
    float local = bufA[tid] + bufA[tid + STHREADS];
    redB[tid] = local;
    __syncthreads();
    for (int s = STHREADS >> 1; s > 0; s >>= 1) {
      if (tid < s) redB[tid] += redB[tid + s];
      __syncthreads();
    }
    if (tid == 0) sh_Z1 = redB[0];
    __syncthreads();
  }

  // p = e/Z1
  const float Z1 = sh_Z1;
  for (int c = tid; c < CAND; c += STHREADS) bufA[c] = bufA[c] / Z1;
  __syncthreads();

  // exact sequential cumsum, wave-parallelized: lane l of wave 0 computes
  // carry + v0 + ... + vl in strict left-to-right order (skipped adds are
  // exact +0.0f) -> bit-identical to a single-thread sequential cumsum.
  if (w == 0) {
    float carry = 0.0f;
    for (int base = lb; base < cs; base += 64) {
      int c = base + l;
      float v = (c < cs) ? bufA[c] : 0.0f;
      float acc = carry;
      for (int j = 0; j < 64; ++j) {
        float t = __shfl(v, j, 64);
        acc += (l >= j) ? t : 0.0f;
      }
      if (c < cs) bufB[c] = acc;
      carry = __shfl(acc, 63, 64);
    }
  }
  __syncthreads();

  // top-p keep flags: drop iff cumsum <= 1-p, never drop last sorted pos
  for (int c = tid; c < CAND; c += STHREADS) {
    unsigned char kf = 0;
    if (c < cs) {
      u32 s = (u32)(cand[c] >> 32);
      if (s >= Ts && (c == cs - 1 || bufB[c] > one_minus_p)) kf = 1;
    }
    keepf[c] = kf;
  }
  __syncthreads();

  // Z2 tree reduce (association identical to round 3)
  {
    float local = 0.0f;
    for (int c = tid; c < CAND; c += STHREADS) {
      if (keepf[c]) {
        u32 s = (u32)(cand[c] >> 32);
        local += expf(s2f(s) - m);
      }
    }
    redA[tid] = local;
    __syncthreads();
    for (int s = STHREADS >> 1; s > 0; s >>= 1) {
      if (tid < s) redA[tid] += redA[tid + s];
      __syncthreads();
    }
    if (tid == 0) sh_Z2 = redA[0];
    __syncthreads();
  }

  // min_p: remove iff (e/Z2) < min_p * (1/Z2)
  {
    const float Z2 = sh_Z2;
    const float rhs = minp * (1.0f / Z2);
    for (int c = tid; c < CAND; c += STHREADS) {
      if (keepf[c]) {
        u32 s = (u32)(cand[c] >> 32);
        float p2 = expf(s2f(s) - m) / Z2;
        if (p2 < rhs) keepf[c] = 0;
      }
    }
  }
  __syncthreads();

  // gumbel-max (JAX categorical), first-index tie-break
  {
    const float TINY = 1.17549435082228750797e-38f;
    u64 best = 0ull;
    for (int c = lb + tid; c < cs; c += STHREADS) {
      if (!keepf[c]) continue;
      u32 s = (u32)(cand[c] >> 32);
      u32 idx = (u32)(cand[c] & 0xFFFFFFFFull);
      float x = s2f(s);
      u32 bits = threefry_bits((u32)b * (u32)V + idx);
      float f = __uint_as_float((bits >> 9) | 0x3f800000u) - 1.0f;
      float u = fmaxf(TINY, f * 1.0f + TINY);
      float g = -logf(-logf(u));
      float sc = g + x;
      u64 key = ((u64)f2s(sc) << 32) | (u64)(0xFFFFFFFFu - idx);
      if (key > best) best = key;
    }
    red64[tid] = best;
    __syncthreads();
    for (int s = STHREADS >> 1; s > 0; s >>= 1) {
      if (tid < s) { u64 o = red64[tid + s]; if (o > red64[tid]) red64[tid] = o; }
      __syncthreads();
    }
    if (tid == 0) out[b] = (int)(0xFFFFFFFFu - (u32)(red64[0] & 0xFFFFFFFFull));
  }
}

extern "C" void kernel_launch(void* const* d_in, const int* in_sizes, int n_in,
                              void* d_out, int out_size, void* d_ws, size_t ws_size,
                              hipStream_t stream) {
  const float* logits = (const float*)d_in[0];
  const float* temps  = (const float*)d_in[1];
  const float* minps  = (const float*)d_in[2];
  const float* topps  = (const float*)d_in[3];
  const int*   topks  = (const int*)d_in[4];
  const int B = in_sizes[1];
  const int V = in_sizes[0] / B;
  (void)n_in; (void)out_size; (void)ws_size;

  // scratch: ghist [B*HBINS] | gcount [B] | gcs [B] | gthr [B] | gcand [B*CAND u64]
  u32* ghist  = (u32*)d_ws;
  u32* gcount = ghist + (size_t)B * HBINS;
  u32* gcs    = gcount + B;
  u32* gthr   = gcs + B;
  u64* gcand  = (u64*)(gthr + B);   // byte offset 4*B*(HBINS+3): 8-aligned for even B

  const int nz = B * HBINS;
  const int slice_len = (((V + NSLICES - 1) / NSLICES) + 3) & ~3;

  zero_kernel<<<dim3((nz + 1023) / 1024), dim3(1024), 0, stream>>>(ghist, nz);
  hist_kernel<<<dim3(B * NSLICES), dim3(HTHREADS), 0, stream>>>(logits, ghist, V, slice_len);
  select_kernel<<<dim3(B), dim3(256), 0, stream>>>(ghist, topks, gthr, gcs, gcount, V);
  collect_kernel<<<dim3(B * NSLICES), dim3(CTHREADS), 0, stream>>>(
      logits, temps, gthr, gcount, gcand, V, slice_len);
  Sampler_73529840107542_kernel<<<dim3(B), dim3(STHREADS), 0, stream>>>(
      minps, topps, topks, gcs, gcand, (int*)d_out, V);
}

// Round 4
// 170.175 us; speedup vs baseline: 1.0403x; 1.0403x over previous
//
#include <hip/hip_runtime.h>
#include <stdint.h>

#define HBINS 8192
#define HSHIFT 19
#define CAND 2048
#define NSLICES 16
#define HTHREADS 256
#define CTHREADS 256
#define STHREADS 1024

typedef unsigned int u32;
typedef unsigned long long u64;

// order-preserving float->uint map (ascending uint == ascending float)
__device__ __forceinline__ u32 f2s(float f) {
  u32 b = __float_as_uint(f);
  return b ^ ((b & 0x80000000u) ? 0xFFFFFFFFu : 0x80000000u);
}
__device__ __forceinline__ float s2f(u32 s) {
  u32 b = (s & 0x80000000u) ? (s ^ 0x80000000u) : ~s;
  return __uint_as_float(b);
}
__device__ __forceinline__ u32 rotl32(u32 x, int r) { return (x << r) | (x >> (32 - r)); }

__device__ __forceinline__ u64 shfl_xor_u64(u64 v, int mask) {
  int lo = __shfl_xor((int)(u32)v, mask, 64);
  int hi = __shfl_xor((int)(u32)(v >> 32), mask, 64);
  return ((u64)(u32)hi << 32) | (u32)lo;
}

// JAX threefry2x32, partitionable counter mode, key = jax.random.key(42) -> (0,42).
__device__ __forceinline__ u32 threefry_bits(u32 ctr) {
  const u32 ks0 = 0u, ks1 = 42u, ks2 = 0x1BD11BDAu ^ 0u ^ 42u;
  u32 x0 = ks0;
  u32 x1 = ctr + ks1;
#define TFR(r) { x0 += x1; x1 = rotl32(x1, (r)); x1 ^= x0; }
  TFR(13) TFR(15) TFR(26) TFR(6)   x0 += ks1; x1 += ks2 + 1u;
  TFR(17) TFR(29) TFR(16) TFR(24)  x0 += ks2; x1 += ks0 + 2u;
  TFR(13) TFR(15) TFR(26) TFR(6)   x0 += ks0; x1 += ks1 + 3u;
  TFR(17) TFR(29) TFR(16) TFR(24)  x0 += ks1; x1 += ks2 + 4u;
  TFR(13) TFR(15) TFR(26) TFR(6)   x0 += ks2; x1 += ks0 + 5u;
#undef TFR
  return x0 ^ x1;
}

// ---------------- zero hist scratch -------------------------------------------
__global__ __launch_bounds__(1024)
void zero_kernel(u32* __restrict__ p, int n) {
  int i = blockIdx.x * 1024 + threadIdx.x;
  if (i < n) p[i] = 0u;
}

// ---------------- per-slice raw-logit histogram (full machine) ----------------
// 8192 bins, packed u16 counts (per-slice count <= slice_len=8000 < 2^16, so no
// cross-field carry), 2 interleaved copies selected by tid&1 to split hot-bin
// same-address atomic streams across lane-parity halves of each wave.
// LDS layout: pair p (bins 2p,2p+1), copy c at hp[2p+c] -> adjacent banks.
__global__ __launch_bounds__(HTHREADS)
void hist_kernel(const float* __restrict__ logits, u32* __restrict__ ghist,
                 int V, int slice_len) {
  const int row = blockIdx.x / NSLICES;
  const int sl  = blockIdx.x % NSLICES;
  const int tid = threadIdx.x;
  __shared__ u32 hp[HBINS];   // HBINS/2 pairs * 2 copies = HBINS u32 = 32 KB
  for (int i = tid; i < HBINS; i += HTHREADS) hp[i] = 0u;
  __syncthreads();
  int rem = V - sl * slice_len;
  if (rem > slice_len) rem = slice_len;
  if (rem < 0) rem = 0;
  const float* src = logits + (size_t)row * (size_t)V + (size_t)sl * slice_len;
  const u32 c = (u32)(tid & 1);
  const int n4 = rem >> 2;
  const float4* p4 = (const float4*)src;
  for (int i = tid; i < n4; i += HTHREADS) {
    float4 w = p4[i];
    u32 b0 = f2s(w.x) >> HSHIFT;
    u32 b1 = f2s(w.y) >> HSHIFT;
    u32 b2 = f2s(w.z) >> HSHIFT;
    u32 b3 = f2s(w.w) >> HSHIFT;
    atomicAdd(&hp[(b0 & ~1u) | c], 1u << ((b0 & 1u) << 4));
    atomicAdd(&hp[(b1 & ~1u) | c], 1u << ((b1 & 1u) << 4));
    atomicAdd(&hp[(b2 & ~1u) | c], 1u << ((b2 & 1u) << 4));
    atomicAdd(&hp[(b3 & ~1u) | c], 1u << ((b3 & 1u) << 4));
  }
  for (int i = (n4 << 2) + tid; i < rem; i += HTHREADS) {
    u32 b = f2s(src[i]) >> HSHIFT;
    atomicAdd(&hp[(b & ~1u) | c], 1u << ((b & 1u) << 4));
  }
  __syncthreads();
  u32* gh = ghist + (size_t)row * HBINS;
  for (int p = tid; p < HBINS / 2; p += HTHREADS) {
    u32 s = hp[2 * p] + hp[2 * p + 1];   // fieldwise sum: each field < 2^16
    if (s) {
      u32 lo = s & 0xFFFFu;
      u32 hi = s >> 16;
      if (lo) atomicAdd(&gh[2 * p], lo);       // sparse merge
      if (hi) atomicAdd(&gh[2 * p + 1], hi);
    }
  }
}

// ---------------- per-row threshold select (tiny) -----------------------------
__global__ __launch_bounds__(256)
void select_kernel(const u32* __restrict__ ghist, const int* __restrict__ topks,
                   u32* __restrict__ gthr, u32* __restrict__ gcs,
                   u32* __restrict__ gcount, int V) {
  const int row = blockIdx.x;
  const int tid = threadIdx.x;
  __shared__ u32 hist[HBINS];   // 32 KB
  __shared__ u32 part[256];     // 32 bins each
  __shared__ u32 chunk[64];     // 128 bins each
  const u32* gh = ghist + (size_t)row * HBINS;
  for (int i = tid; i < HBINS; i += 256) hist[i] = gh[i];
  __syncthreads();
  {
    u32 s = 0;
    for (int j = 0; j < 32; ++j) s += hist[tid * 32 + j];
    part[tid] = s;
  }
  __syncthreads();
  if (tid < 64) {
    chunk[tid] = part[tid * 4] + part[tid * 4 + 1] + part[tid * 4 + 2] + part[tid * 4 + 3];
  }
  __syncthreads();
  if (tid == 0) {
    int k = topks[row];
    if (k < 1) k = 1;
    if (k > V) k = V;
    const u32 ku = (u32)k;
    u32 acc = 0;
    int cstar = 0;
    for (int c = 63; c >= 0; --c) {
      if (acc + chunk[c] >= ku) { cstar = c; break; }
      acc += chunk[c];
    }
    int pstar = cstar * 4;
    for (int p = cstar * 4 + 3; p >= cstar * 4; --p) {
      if (acc + part[p] >= ku) { pstar = p; break; }
      acc += part[p];
    }
    int bstar = pstar * 32;
    for (int bq = pstar * 32 + 31; bq >= pstar * 32; --bq) {
      acc += hist[bq];
      if (acc >= ku) { bstar = bq; break; }
    }
    gthr[row] = (u32)bstar << HSHIFT;
    gcs[row] = (acc < (u32)CAND ? acc : (u32)CAND);
    gcount[row] = 0u;
  }
}

// ---------------- per-slice collect (full machine, no hist traffic) -----------
__global__ __launch_bounds__(CTHREADS)
void collect_kernel(const float* __restrict__ logits,
                    const float* __restrict__ temps,
                    const u32* __restrict__ gthr,
                    u32* __restrict__ gcount,
                    u64* __restrict__ gcand, int V, int slice_len) {
  const int row = blockIdx.x / NSLICES;
  const int sl  = blockIdx.x % NSLICES;
  const int tid = threadIdx.x;

  __shared__ u64 stage[CAND];
  __shared__ int sh_cnt, sh_base;
  if (tid == 0) sh_cnt = 0;
  __syncthreads();

  const u32 thr = gthr[row];
  const float t = temps[row];
  int rem = V - sl * slice_len;
  if (rem > slice_len) rem = slice_len;
  if (rem < 0) rem = 0;
  const float* src = logits + (size_t)row * (size_t)V + (size_t)sl * slice_len;
  const u32 ibase = (u32)(sl * slice_len);
  const int n4 = rem >> 2;
  const float4* p4 = (const float4*)src;
  for (int i = tid; i < n4; i += CTHREADS) {
    float4 w = p4[i];
    if (f2s(w.x) >= thr) { int pos = atomicAdd(&sh_cnt, 1); if (pos < CAND) stage[pos] = ((u64)f2s(w.x / t) << 32) | (ibase + 4u * i + 0u); }
    if (f2s(w.y) >= thr) { int pos = atomicAdd(&sh_cnt, 1); if (pos < CAND) stage[pos] = ((u64)f2s(w.y / t) << 32) | (ibase + 4u * i + 1u); }
    if (f2s(w.z) >= thr) { int pos = atomicAdd(&sh_cnt, 1); if (pos < CAND) stage[pos] = ((u64)f2s(w.z / t) << 32) | (ibase + 4u * i + 2u); }
    if (f2s(w.w) >= thr) { int pos = atomicAdd(&sh_cnt, 1); if (pos < CAND) stage[pos] = ((u64)f2s(w.w / t) << 32) | (ibase + 4u * i + 3u); }
  }
  for (int i = (n4 << 2) + tid; i < rem; i += CTHREADS) {
    float l = src[i];
    if (f2s(l) >= thr) { int pos = atomicAdd(&sh_cnt, 1); if (pos < CAND) stage[pos] = ((u64)f2s(l / t) << 32) | (ibase + (u32)i); }
  }
  __syncthreads();
  int n = sh_cnt;
  if (n > CAND) n = CAND;
  if (tid == 0) sh_base = (int)atomicAdd(&gcount[row], (u32)n);
  __syncthreads();
  const int base = sh_base;
  u64* gc = gcand + (size_t)row * CAND;
  for (int i = tid; i < n; i += CTHREADS) {
    int dst = base + i;
    if (dst < CAND) gc[dst] = stage[i];
  }
}

// ---------------- per-row: hybrid reg/LDS sort + softmax chain + gumbel -------
__global__ __launch_bounds__(STHREADS)
void Sampler_73529840107542_kernel(const float* __restrict__ minps,
                                   const float* __restrict__ topps,
                                   const int* __restrict__ topks,
                                   const u32* __restrict__ gcs,
                                   const u64* __restrict__ gcand,
                                   int* __restrict__ out, int V) {
  const int b = blockIdx.x;
  const int tid = threadIdx.x;
  const int w = tid >> 6;
  const int l = tid & 63;
  const float one_minus_p = 1.0f - topps[b];
  const float minp = minps[b];
  int k = topks[b];
  if (k < 1) k = 1;
  if (k > V) k = V;

  __shared__ __align__(16) unsigned char arena[34816];
  u64* cand   = (u64*)(arena);              // [0,16384)
  float* bufA = (float*)(arena + 16384);    // [16384,24576) e / p
  float* bufB = (float*)(arena + 24576);    // [24576,32768) cumsum
  unsigned char* keepf = arena + 32768;     // [32768,34816)
  u64* red64  = (u64*)(arena + 16384);      // aliases bufA (argmax stage)
  float* redA = (float*)(arena + 16384);    // aliases bufA (Z2 stage)
  float* redB = (float*)(arena + 24576);    // aliases bufB (Z1 stage)

  __shared__ int sh_lb;
  __shared__ u32 sh_Ts;
  __shared__ float sh_m, sh_Z1, sh_Z2;

  const int cs = (int)gcs[b];
  const u64* gc = gcand + (size_t)b * CAND;
  const int e_lo = (w << 7) + l;      // wave w owns elements [w*128, w*128+128)
  const int e_hi = e_lo + 64;
  const u64 SENT = 0xFFFFFFFFFFFFFFFFull;
  u64 k0 = (e_lo < cs) ? gc[e_lo] : SENT;
  u64 k1 = (e_hi < cs) ? gc[e_hi] : SENT;

  // bitonic sort over the smallest power-of-2 span P >= cs (uniform per block;
  // slots [cs,P) hold SENT so [0,cs) ends up ascending == JAX stable argsort).
  // strides <=32: shfl_xor; stride 64: register swap; strides >=128: LDS.
  int P = 64;
  while (P < cs) P <<= 1;
  for (int size = 2; size <= P; size <<= 1) {
    for (int s = size >> 1; s > 0; s >>= 1) {
      if (s >= 128) {
        cand[e_lo] = k0; cand[e_hi] = k1;
        __syncthreads();
        u64 p0 = cand[e_lo ^ s], p1 = cand[e_hi ^ s];
        {
          bool keepmin = (((e_lo & s) == 0) == ((e_lo & size) == 0));
          if (keepmin ? (p0 < k0) : (p0 > k0)) k0 = p0;
        }
        {
          bool keepmin = (((e_hi & s) == 0) == ((e_hi & size) == 0));
          if (keepmin ? (p1 < k1) : (p1 > k1)) k1 = p1;
        }
        __syncthreads();
      } else if (s == 64) {
        bool asc = ((e_lo & size) == 0);   // e_hi has same direction (size>=128)
        if ((k0 > k1) == asc) { u64 t = k0; k0 = k1; k1 = t; }
      } else {
        u64 p0 = shfl_xor_u64(k0, s);
        u64 p1 = shfl_xor_u64(k1, s);
        {
          bool keepmin = (((l & s) == 0) == ((e_lo & size) == 0));
          if (keepmin ? (p0 < k0) : (p0 > k0)) k0 = p0;
        }
        {
          bool keepmin = (((l & s) == 0) == ((e_hi & size) == 0));
          if (keepmin ? (p1 < k1) : (p1 > k1)) k1 = p1;
        }
      }
    }
  }
  cand[e_lo] = k0; cand[e_hi] = k1;
  __syncthreads();

  if (tid == 0) {
    int ti = cs - k; if (ti < 0) ti = 0;
    sh_Ts = (u32)(cand[ti] >> 32);             // k-th largest x (exact)
    sh_m  = s2f((u32)(cand[cs - 1] >> 32));    // row max
  }
  __syncthreads();
  const u32 Ts = sh_Ts;
  const float m = sh_m;

  // first survivor slot (values >= Ts form a contiguous suffix of [0,cs))
  for (int c = tid; c < cs; c += STHREADS) {
    u32 s = (u32)(cand[c] >> 32);
    if (s >= Ts && (c == 0 || (u32)(cand[c - 1] >> 32) < Ts)) sh_lb = c;
  }
  __syncthreads();
  const int lb = sh_lb;

  // e = exp(x - m); exact 0 for masked / pad
  for (int c = tid; c < CAND; c += STHREADS) {
    float e = 0.0f;
    if (c < cs) {
      u32 s = (u32)(cand[c] >> 32);
      if (s >= Ts) e = expf(s2f(s) - m);
    }
    bufA[c] = e;
  }
  __syncthreads();

  // Z1 tree reduce (association identical to round 3)
  {
    float local = bufA[tid] + bufA[tid + STHREADS];
    redB[tid] = local;
    __syncthreads();
    for (int s = STHREADS >> 1; s > 0; s >>= 1) {
      if (tid < s) redB[tid] += redB[tid + s];
      __syncthreads();
    }
    if (tid == 0) sh_Z1 = redB[0];
    __syncthreads();
  }

  // p = e/Z1
  const float Z1 = sh_Z1;
  for (int c = tid; c < CAND; c += STHREADS) bufA[c] = bufA[c] / Z1;
  __syncthreads();

  // exact sequential cumsum, wave-parallelized: lane l of wave 0 computes
  // carry + v0 + ... + vl in strict left-to-right order (skipped adds are
  // exact +0.0f) -> bit-identical to a single-thread sequential cumsum.
  // Broadcast of lane j's value uses v_readlane (constant j, fully unrolled):
  // VALU op into SGPR, no ds_bpermute / lgkmcnt dependency in the add chain.
  if (w == 0) {
    float carry = 0.0f;
    for (int base = lb; base < cs; base += 64) {
      int c = base + l;
      float v = (c < cs) ? bufA[c] : 0.0f;
      u32 vb = __float_as_uint(v);
      float acc = carry;
#pragma unroll
      for (int j = 0; j < 64; ++j) {
        float t = __uint_as_float(__builtin_amdgcn_readlane(vb, j));
        acc += (l >= j) ? t : 0.0f;
      }
      if (c < cs) bufB[c] = acc;
      carry = __uint_as_float(__builtin_amdgcn_readlane(__float_as_uint(acc), 63));
    }
  }
  __syncthreads();

  // top-p keep flags: drop iff cumsum <= 1-p, never drop last sorted pos
  for (int c = tid; c < CAND; c += STHREADS) {
    unsigned char kf = 0;
    if (c < cs) {
      u32 s = (u32)(cand[c] >> 32);
      if (s >= Ts && (c == cs - 1 || bufB[c] > one_minus_p)) kf = 1;
    }
    keepf[c] = kf;
  }
  __syncthreads();

  // Z2 tree reduce (association identical to round 3)
  {
    float local = 0.0f;
    for (int c = tid; c < CAND; c += STHREADS) {
      if (keepf[c]) {
        u32 s = (u32)(cand[c] >> 32);
        local += expf(s2f(s) - m);
      }
    }
    redA[tid] = local;
    __syncthreads();
    for (int s = STHREADS >> 1; s > 0; s >>= 1) {
      if (tid < s) redA[tid] += redA[tid + s];
      __syncthreads();
    }
    if (tid == 0) sh_Z2 = redA[0];
    __syncthreads();
  }

  // min_p: remove iff (e/Z2) < min_p * (1/Z2)
  {
    const float Z2 = sh_Z2;
    const float rhs = minp * (1.0f / Z2);
    for (int c = tid; c < CAND; c += STHREADS) {
      if (keepf[c]) {
        u32 s = (u32)(cand[c] >> 32);
        float p2 = expf(s2f(s) - m) / Z2;
        if (p2 < rhs) keepf[c] = 0;
      }
    }
  }
  __syncthreads();

  // gumbel-max (JAX categorical), first-index tie-break
  {
    const float TINY = 1.17549435082228750797e-38f;
    u64 best = 0ull;
    for (int c = lb + tid; c < cs; c += STHREADS) {
      if (!keepf[c]) continue;
      u32 s = (u32)(cand[c] >> 32);
      u32 idx = (u32)(cand[c] & 0xFFFFFFFFull);
      float x = s2f(s);
      u32 bits = threefry_bits((u32)b * (u32)V + idx);
      float f = __uint_as_float((bits >> 9) | 0x3f800000u) - 1.0f;
      float u = fmaxf(TINY, f * 1.0f + TINY);
      float g = -logf(-logf(u));
      float sc = g + x;
      u64 key = ((u64)f2s(sc) << 32) | (u64)(0xFFFFFFFFu - idx);
      if (key > best) best = key;
    }
    red64[tid] = best;
    __syncthreads();
    for (int s = STHREADS >> 1; s > 0; s >>= 1) {
      if (tid < s) { u64 o = red64[tid + s]; if (o > red64[tid]) red64[tid] = o; }
      __syncthreads();
    }
    if (tid == 0) out[b] = (int)(0xFFFFFFFFu - (u32)(red64[0] & 0xFFFFFFFFull));
  }
}

extern "C" void kernel_launch(void* const* d_in, const int* in_sizes, int n_in,
                              void* d_out, int out_size, void* d_ws, size_t ws_size,
                              hipStream_t stream) {
  const float* logits = (const float*)d_in[0];
  const float* temps  = (const float*)d_in[1];
  const float* minps  = (const float*)d_in[2];
  const float* topps  = (const float*)d_in[3];
  const int*   topks  = (const int*)d_in[4];
  const int B = in_sizes[1];
  const int V = in_sizes[0] / B;
  (void)n_in; (void)out_size; (void)ws_size;

  // scratch: ghist [B*HBINS] | gcount [B] | gcs [B] | gthr [B] | gcand [B*CAND u64]
  u32* ghist  = (u32*)d_ws;
  u32* gcount = ghist + (size_t)B * HBINS;
  u32* gcs    = gcount + B;
  u32* gthr   = gcs + B;
  u64* gcand  = (u64*)(gthr + B);   // byte offset 4*B*(HBINS+3): 8-aligned for even B

  const int nz = B * HBINS;
  const int slice_len = (((V + NSLICES - 1) / NSLICES) + 3) & ~3;

  zero_kernel<<<dim3((nz + 1023) / 1024), dim3(1024), 0, stream>>>(ghist, nz);
  hist_kernel<<<dim3(B * NSLICES), dim3(HTHREADS), 0, stream>>>(logits, ghist, V, slice_len);
  select_kernel<<<dim3(B), dim3(256), 0, stream>>>(ghist, topks, gthr, gcs, gcount, V);
  collect_kernel<<<dim3(B * NSLICES), dim3(CTHREADS), 0, stream>>>(
      logits, temps, gthr, gcount, gcand, V, slice_len);
  Sampler_73529840107542_kernel<<<dim3(B), dim3(STHREADS), 0, stream>>>(
      minps, topps, topks, gcs, gcand, (int*)d_out, V);
}